// Round 3
// baseline (127.068 us; speedup 1.0000x reference)
//
#include <hip/hip_runtime.h>

// CensusLoss = mean |census(pred)-census(target)| = mismatch_count / (8*48*512*512).
// R14 kernel — R7 compute (verbatim) + cross-tile software pipeline.
// Each block owns TWO vertically-adjacent 64x32 tiles, double-buffered LDS.
// Tile B's global loads are issued into REGISTERS before compute(A), so HBM
// latency hides under compute; gray+LDS-write for B lands after compute(A).
//
// Session ledger (why this exact shape):
//  - stage -> ONE sync -> ONE uniform compute site per tile. Divergent
//    wave-split pipelines (R4-R6) spill to scratch, regress 1.6-2x. Banned.
//  - In-tile sandwich overlap (R8): no gain (barrier vmcnt drain sits in the
//    critical path when loads and consumers are in the same phase). R14 moves
//    the drain AFTER a full compute phase instead.
//  - Symmetry-halving (R9-R11): exact but never faster. Banned.
//  - Ballot/popcount SALU accumulation (R12): census 26 -> 55us. Scalar unit
//    is CU-shared; v_cmp->SALU chains stall issue. Banned.
//  - RPT=8 / 64x64 (R13): neutral -> compute is NOT LDS-issue-bound.
//    Round-1 counters: staging runs at ~1-2 TB/s effective (latency-bound,
//    phase-serialized with compute). THE remaining lever is overlap.
//  - Edge blocks now take the float4 path too: reflected x-halo chunks load
//    scalar-reversed into the same register set (38/684 sets per edge block).
// Remaining: ~72us harness poison fills (fixed), ~8us HBM floor, compute.

#define BATCH 8
#define HH 512
#define WW 512
#define PLANE (HH * WW)
#define TW 64
#define TH 32
#define SCOLS 72          // staged cols: gx = tx0-4+lx
#define HROWS 38          // halo rows:  gy = ty0-3+hy
#define KPR 18            // float4 chunks per halo row (72/4)
#define PITCH 44
#define NT 512
#define LDSZ (SCOLS * PITCH)   // 3168 dwords per array
#define NSETS (HROWS * KPR)    // 684 float4-sets per tile
#define XSETS (NSETS - NT)     // 172 threads carry a second set

__device__ __forceinline__ int refl(int v, int n) {
    return v < 0 ? -v : (v >= n ? 2 * n - 2 - v : v);
}
__device__ __forceinline__ int cbase(int lx) {      // swizzled column base
    return lx * PITCH + (((lx >> 2) & 7) << 2);     // stays 0 mod 4 -> 16B cols
}
__device__ __forceinline__ float gray(float r, float g, float b) {
    return 0.299f * r + 0.587f * g + 0.114f * b;
}

// One float4-chunk of staging input: 6 float4 = 24 VGPRs.
struct Set6 { float4 pr, pg, pc, tr, tg, tc; };

// Issue the global loads for set sidx of tile (ty0, tx0). Elements arrive
// already in column order (reflected x-halo chunks load scalar-reversed).
__device__ __forceinline__ void prefetch_set(const float* __restrict__ pb,
                                             const float* __restrict__ tb,
                                             int ty0, int tx0, int sidx, Set6& s) {
    const int hy  = sidx / KPR;
    const int k   = sidx - hy * KPR;
    const int gy  = refl(ty0 + hy - 3, HH);
    const int gx0 = tx0 - 4 + 4 * k;
    if (gx0 >= 0 && gx0 <= WW - 4) {
        const int off = gy * WW + gx0;               // 16B-aligned
        s.pr = *(const float4*)(pb + off);
        s.pg = *(const float4*)(pb + off + PLANE);
        s.pc = *(const float4*)(pb + off + 2 * PLANE);
        s.tr = *(const float4*)(tb + off);
        s.tg = *(const float4*)(tb + off + PLANE);
        s.tc = *(const float4*)(tb + off + 2 * PLANE);
    } else {
        // reflected: col lx+i needs gx = g0 - i (left: refl(-4+i)=4-i,
        // right: refl(512+i)=510-i). Load reversed so Set6 is in col order.
        const int g0 = (gx0 < 0) ? 4 : 510;
        const int ro = gy * WW + g0;
        s.pr = make_float4(pb[ro], pb[ro - 1], pb[ro - 2], pb[ro - 3]);
        s.pg = make_float4(pb[ro + PLANE], pb[ro - 1 + PLANE], pb[ro - 2 + PLANE], pb[ro - 3 + PLANE]);
        s.pc = make_float4(pb[ro + 2 * PLANE], pb[ro - 1 + 2 * PLANE], pb[ro - 2 + 2 * PLANE], pb[ro - 3 + 2 * PLANE]);
        s.tr = make_float4(tb[ro], tb[ro - 1], tb[ro - 2], tb[ro - 3]);
        s.tg = make_float4(tb[ro + PLANE], tb[ro - 1 + PLANE], tb[ro - 2 + PLANE], tb[ro - 3 + PLANE]);
        s.tc = make_float4(tb[ro + 2 * PLANE], tb[ro - 1 + 2 * PLANE], tb[ro - 2 + 2 * PLANE], tb[ro - 3 + 2 * PLANE]);
    }
}

// Gray-convert and scatter set sidx into the column-major swizzled LDS tile.
__device__ __forceinline__ void write_set(float* __restrict__ sP,
                                          float* __restrict__ sT,
                                          int sidx, const Set6& s) {
    const int hy = sidx / KPR;
    const int k  = sidx - hy * KPR;
    const int cb = cbase(4 * k) + hy;   // cbase(lx+i) = cbase(lx) + i*PITCH
    sP[cb + 0 * PITCH] = gray(s.pr.x, s.pg.x, s.pc.x);
    sP[cb + 1 * PITCH] = gray(s.pr.y, s.pg.y, s.pc.y);
    sP[cb + 2 * PITCH] = gray(s.pr.z, s.pg.z, s.pc.z);
    sP[cb + 3 * PITCH] = gray(s.pr.w, s.pg.w, s.pc.w);
    sT[cb + 0 * PITCH] = gray(s.tr.x, s.tg.x, s.tc.x);
    sT[cb + 1 * PITCH] = gray(s.tr.y, s.tg.y, s.tc.y);
    sT[cb + 2 * PITCH] = gray(s.tr.z, s.tg.z, s.tc.z);
    sT[cb + 3 * PITCH] = gray(s.tr.w, s.tg.w, s.tc.w);
}

// Load 10 consecutive column floats (16B-aligned) into registers.
__device__ __forceinline__ void load_col10(const float* col, float (&w)[10]) {
    const float4 a = *(const float4*)(col);
    const float4 b = *(const float4*)(col + 4);
    const float2 d = *(const float2*)(col + 8);
    w[0] = a.x; w[1] = a.y; w[2] = a.z; w[3] = a.w;
    w[4] = b.x; w[5] = b.y; w[6] = b.z; w[7] = b.w;
    w[8] = d.x; w[9] = d.y;
}

// R7-verbatim compute phase: per-lane predicated mismatch count for one tile.
__device__ __forceinline__ int compute_tile(const float* __restrict__ sP,
                                            const float* __restrict__ sT) {
    const int wv  = threadIdx.x >> 6;   // wave == 4-row band
    const int c   = threadIdx.x & 63;   // pixel column in tile
    const int pr0 = wv * 4;             // first pixel row (0,4,..,28)

    float wP[10], wT[10], cP[4], cT[4];
    int cnt = 0;
    load_col10(&sP[cbase(c + 4) + pr0], wP);        // dx = 0 column (centers)
    load_col10(&sT[cbase(c + 4) + pr0], wT);
    #pragma unroll
    for (int p = 0; p < 4; ++p) { cP[p] = wP[3 + p]; cT[p] = wT[3 + p]; }
    #pragma unroll
    for (int p = 0; p < 4; ++p) {
        #pragma unroll
        for (int dy = -3; dy <= 3; ++dy) {
            if (dy == 0) continue;                  // skip center
            cnt += ((cP[p] > wP[3 + p + dy]) != (cT[p] > wT[3 + p + dy])) ? 1 : 0;
        }
    }
    #pragma unroll
    for (int t = 0; t < 6; ++t) {
        const int lx = c + 1 + (t < 3 ? t : t + 1); // dx = -3..3, dx != 0
        load_col10(&sP[cbase(lx) + pr0], wP);
        load_col10(&sT[cbase(lx) + pr0], wT);
        #pragma unroll
        for (int p = 0; p < 4; ++p) {
            #pragma unroll
            for (int dy = -3; dy <= 3; ++dy)
                cnt += ((cP[p] > wP[3 + p + dy]) != (cT[p] > wT[3 + p + dy])) ? 1 : 0;
        }
    }
    return cnt;
}

__global__ __launch_bounds__(NT, 4)
void census_fused(const float* __restrict__ pred,
                  const float* __restrict__ target,
                  float* __restrict__ out) {
    __shared__ __align__(16) float sP0[LDSZ];
    __shared__ __align__(16) float sT0[LDSZ];
    __shared__ __align__(16) float sP1[LDSZ];
    __shared__ __align__(16) float sT1[LDSZ];

    const int b    = blockIdx.z;
    const int tx0  = blockIdx.x * TW;
    const int ty0A = (blockIdx.y * 2 + 0) * TH;     // two vertically-adjacent tiles
    const int ty0B = (blockIdx.y * 2 + 1) * TH;
    const float* __restrict__ pb = pred   + (size_t)b * 3 * PLANE;
    const float* __restrict__ tb = target + (size_t)b * 3 * PLANE;
    const int  tid = threadIdx.x;
    const bool h1  = tid < XSETS;                   // carries a second set

    Set6 a0, a1;

    // ---- stage tile A (prologue, exposed) ----
    prefetch_set(pb, tb, ty0A, tx0, tid, a0);
    if (h1) prefetch_set(pb, tb, ty0A, tx0, tid + NT, a1);
    write_set(sP0, sT0, tid, a0);
    if (h1) write_set(sP0, sT0, tid + NT, a1);
    __syncthreads();

    // ---- issue tile B loads -> compute A (loads in flight) -> write B ----
    prefetch_set(pb, tb, ty0B, tx0, tid, a0);
    if (h1) prefetch_set(pb, tb, ty0B, tx0, tid + NT, a1);
    int cnt = compute_tile(sP0, sT0);
    write_set(sP1, sT1, tid, a0);
    if (h1) write_set(sP1, sT1, tid + NT, a1);
    __syncthreads();

    cnt += compute_tile(sP1, sT1);

    // Reduce: 64-lane shuffle, cross-wave LDS, one atomic per block.
    #pragma unroll
    for (int o = 32; o > 0; o >>= 1) cnt += __shfl_down(cnt, o, 64);
    __shared__ int wsum[8];
    const int wv = threadIdx.x >> 6;
    if ((threadIdx.x & 63) == 0) wsum[wv] = cnt;
    __syncthreads();
    if (threadIdx.x == 0) {
        int tot = 0;
        #pragma unroll
        for (int w = 0; w < 8; ++w) tot += wsum[w];
        // N = 8 * 48 * 512 * 512 = 100663296
        atomicAdd(out, (float)tot * (1.0f / 100663296.0f));
    }
}

extern "C" void kernel_launch(void* const* d_in, const int* in_sizes, int n_in,
                              void* d_out, int out_size, void* d_ws, size_t ws_size,
                              hipStream_t stream) {
    const float* pred   = (const float*)d_in[0];
    const float* target = (const float*)d_in[1];
    float* out = (float*)d_out;

    hipMemsetAsync(out, 0, sizeof(float), stream);   // d_out poisoned 0xAA

    dim3 grid(WW / TW, HH / (2 * TH), BATCH);        // (8, 8, 8) = 512 blocks
    census_fused<<<grid, NT, 0, stream>>>(pred, target, out);
}

// Round 4
// 123.554 us; speedup vs baseline: 1.0284x; 1.0284x over previous
//
#include <hip/hip_runtime.h>

// CensusLoss = mean |census(pred)-census(target)| = mismatch_count / (8*48*512*512).
// R15 kernel — R7 compute (verbatim) + cross-tile pipeline, spill-proof.
// Two vertically-adjacent 64x32 tiles per block, double-buffered LDS.
// ONE set per thread (6 named float4, 24 VGPR, unconditional) is prefetched
// for tile B before compute(A); the 172-set tail is staged after compute(A).
//
// Session ledger (why this exact shape):
//  - Divergent wave-split pipelines (R4-R6): scratch spills, 1.6-2x. Banned.
//  - In-tile sandwich (R8): no gain. Cross-tile version moves the vmcnt
//    drain AFTER a full compute phase -> mechanism confirmed in R14.
//  - Symmetry-halving (R9-R11): exact, never faster. Banned.
//  - Ballot/popcount SALU accumulation (R12): 26 -> 55us. Scalar unit is
//    CU-shared; v_cmp->SALU chains stall issue. Banned.
//  - RPT=8 (R13): neutral -> compute not LDS-issue-bound.
//  - R14: full-tile-B register prefetch (2x Set6, if(h1) conditional live)
//    -> compiler spilled (WRITE_SIZE 2->73.7MB, FETCH 50->90.9MB), census 58us.
//    Lesson: prefetch state must be SMALL, NAMED, UNCONDITIONALLY live.
//  - R15 (this): 1 set/thread prefetch (24 VGPR), uniform; tail staged after
//    compute(A); sched_barrier(0) pins load issue above compute.
// Pass/fail counters: WRITE_SIZE ~2MB (no spill), FETCH ~50-55MB.

#define BATCH 8
#define HH 512
#define WW 512
#define PLANE (HH * WW)
#define TW 64
#define TH 32
#define SCOLS 72          // staged cols: gx = tx0-4+lx
#define HROWS 38          // halo rows:  gy = ty0-3+hy
#define KPR 18            // float4 chunks per halo row (72/4)
#define PITCH 44
#define NT 512
#define LDSZ (SCOLS * PITCH)   // 3168 dwords per array
#define NSETS (HROWS * KPR)    // 684 float4-sets per tile
#define XSETS (NSETS - NT)     // 172 tail sets

__device__ __forceinline__ int refl(int v, int n) {
    return v < 0 ? -v : (v >= n ? 2 * n - 2 - v : v);
}
__device__ __forceinline__ int cbase(int lx) {      // swizzled column base
    return lx * PITCH + (((lx >> 2) & 7) << 2);     // stays 0 mod 4 -> 16B cols
}
__device__ __forceinline__ float gray(float r, float g, float b) {
    return 0.299f * r + 0.587f * g + 0.114f * b;
}

// Stage one 4-column set (load + gray + LDS write). Block-uniform `fast`.
__device__ __forceinline__ void stage_set(const float* __restrict__ pb,
                                          const float* __restrict__ tb,
                                          int ty0, int tx0, int sidx,
                                          float* __restrict__ sP,
                                          float* __restrict__ sT, bool fast) {
    const int hy = sidx / KPR;
    const int k  = sidx - hy * KPR;
    const int gy = refl(ty0 + hy - 3, HH);
    const int cb = cbase(4 * k) + hy;   // cbase(4k+i) = cbase(4k) + i*PITCH
    if (fast) {
        const int off = gy * WW + tx0 - 4 + 4 * k;            // 16B-aligned
        const float4 pr = *(const float4*)(pb + off);
        const float4 pg = *(const float4*)(pb + off + PLANE);
        const float4 pc = *(const float4*)(pb + off + 2 * PLANE);
        const float4 tr = *(const float4*)(tb + off);
        const float4 tg = *(const float4*)(tb + off + PLANE);
        const float4 tc = *(const float4*)(tb + off + 2 * PLANE);
        sP[cb + 0 * PITCH] = gray(pr.x, pg.x, pc.x);
        sP[cb + 1 * PITCH] = gray(pr.y, pg.y, pc.y);
        sP[cb + 2 * PITCH] = gray(pr.z, pg.z, pc.z);
        sP[cb + 3 * PITCH] = gray(pr.w, pg.w, pc.w);
        sT[cb + 0 * PITCH] = gray(tr.x, tg.x, tc.x);
        sT[cb + 1 * PITCH] = gray(tr.y, tg.y, tc.y);
        sT[cb + 2 * PITCH] = gray(tr.z, tg.z, tc.z);
        sT[cb + 3 * PITCH] = gray(tr.w, tg.w, tc.w);
    } else {
        #pragma unroll
        for (int i = 0; i < 4; ++i) {
            const int gx  = refl(tx0 - 4 + 4 * k + i, WW);
            const int off = gy * WW + gx;
            sP[cb + i * PITCH] = gray(pb[off], pb[off + PLANE], pb[off + 2 * PLANE]);
            sT[cb + i * PITCH] = gray(tb[off], tb[off + PLANE], tb[off + 2 * PLANE]);
        }
    }
}

// Load 10 consecutive column floats (16B-aligned) into registers.
__device__ __forceinline__ void load_col10(const float* col, float (&w)[10]) {
    const float4 a = *(const float4*)(col);
    const float4 b = *(const float4*)(col + 4);
    const float2 d = *(const float2*)(col + 8);
    w[0] = a.x; w[1] = a.y; w[2] = a.z; w[3] = a.w;
    w[4] = b.x; w[5] = b.y; w[6] = b.z; w[7] = b.w;
    w[8] = d.x; w[9] = d.y;
}

// R7-verbatim compute phase: per-lane predicated mismatch count for one tile.
__device__ __forceinline__ int compute_tile(const float* __restrict__ sP,
                                            const float* __restrict__ sT) {
    const int wv  = threadIdx.x >> 6;   // wave == 4-row band
    const int c   = threadIdx.x & 63;   // pixel column in tile
    const int pr0 = wv * 4;             // first pixel row (0,4,..,28)

    float wP[10], wT[10], cP[4], cT[4];
    int cnt = 0;
    load_col10(&sP[cbase(c + 4) + pr0], wP);        // dx = 0 column (centers)
    load_col10(&sT[cbase(c + 4) + pr0], wT);
    #pragma unroll
    for (int p = 0; p < 4; ++p) { cP[p] = wP[3 + p]; cT[p] = wT[3 + p]; }
    #pragma unroll
    for (int p = 0; p < 4; ++p) {
        #pragma unroll
        for (int dy = -3; dy <= 3; ++dy) {
            if (dy == 0) continue;                  // skip center
            cnt += ((cP[p] > wP[3 + p + dy]) != (cT[p] > wT[3 + p + dy])) ? 1 : 0;
        }
    }
    #pragma unroll
    for (int t = 0; t < 6; ++t) {
        const int lx = c + 1 + (t < 3 ? t : t + 1); // dx = -3..3, dx != 0
        load_col10(&sP[cbase(lx) + pr0], wP);
        load_col10(&sT[cbase(lx) + pr0], wT);
        #pragma unroll
        for (int p = 0; p < 4; ++p) {
            #pragma unroll
            for (int dy = -3; dy <= 3; ++dy)
                cnt += ((cP[p] > wP[3 + p + dy]) != (cT[p] > wT[3 + p + dy])) ? 1 : 0;
        }
    }
    return cnt;
}

__global__ __launch_bounds__(NT, 4)
void census_fused(const float* __restrict__ pred,
                  const float* __restrict__ target,
                  float* __restrict__ out) {
    __shared__ __align__(16) float sP0[LDSZ];
    __shared__ __align__(16) float sT0[LDSZ];
    __shared__ __align__(16) float sP1[LDSZ];
    __shared__ __align__(16) float sT1[LDSZ];

    const int b    = blockIdx.z;
    const int tx0  = blockIdx.x * TW;
    const int ty0A = (blockIdx.y * 2 + 0) * TH;     // two vertically-adjacent tiles
    const int ty0B = (blockIdx.y * 2 + 1) * TH;
    const float* __restrict__ pb = pred   + (size_t)b * 3 * PLANE;
    const float* __restrict__ tb = target + (size_t)b * 3 * PLANE;
    const int  tid  = threadIdx.x;
    const bool fastx = (blockIdx.x >= 1 && blockIdx.x <= 6);

    // ---- stage tile A fully (prologue, exposed) ----
    for (int idx = tid; idx < NSETS; idx += NT)
        stage_set(pb, tb, ty0A, tx0, idx, sP0, sT0, fastx);
    __syncthreads();

    // ---- prefetch ONE set of tile B per thread: 6 named float4, uniform ----
    float4 pr, pg, pc, tr, tg, tc;
    int pcb;
    {
        const int hy = tid / KPR;
        const int k  = tid - hy * KPR;
        const int gy = refl(ty0B + hy - 3, HH);
        pcb = cbase(4 * k) + hy;
        if (fastx) {
            const int off = gy * WW + tx0 - 4 + 4 * k;        // 16B-aligned
            pr = *(const float4*)(pb + off);
            pg = *(const float4*)(pb + off + PLANE);
            pc = *(const float4*)(pb + off + 2 * PLANE);
            tr = *(const float4*)(tb + off);
            tg = *(const float4*)(tb + off + PLANE);
            tc = *(const float4*)(tb + off + 2 * PLANE);
        } else {                                              // block-uniform
            const int o0 = gy * WW + refl(tx0 - 4 + 4 * k + 0, WW);
            const int o1 = gy * WW + refl(tx0 - 4 + 4 * k + 1, WW);
            const int o2 = gy * WW + refl(tx0 - 4 + 4 * k + 2, WW);
            const int o3 = gy * WW + refl(tx0 - 4 + 4 * k + 3, WW);
            pr = make_float4(pb[o0], pb[o1], pb[o2], pb[o3]);
            pg = make_float4(pb[o0 + PLANE], pb[o1 + PLANE], pb[o2 + PLANE], pb[o3 + PLANE]);
            pc = make_float4(pb[o0 + 2 * PLANE], pb[o1 + 2 * PLANE], pb[o2 + 2 * PLANE], pb[o3 + 2 * PLANE]);
            tr = make_float4(tb[o0], tb[o1], tb[o2], tb[o3]);
            tg = make_float4(tb[o0 + PLANE], tb[o1 + PLANE], tb[o2 + PLANE], tb[o3 + PLANE]);
            tc = make_float4(tb[o0 + 2 * PLANE], tb[o1 + 2 * PLANE], tb[o2 + 2 * PLANE], tb[o3 + 2 * PLANE]);
        }
    }
    __builtin_amdgcn_sched_barrier(0);   // pin the prefetch issue above compute(A)

    // ---- compute tile A while tile B loads are in flight ----
    int cnt = compute_tile(sP0, sT0);

    // ---- land prefetched set, stage 172-set tail, sync ----
    sP1[pcb + 0 * PITCH] = gray(pr.x, pg.x, pc.x);
    sP1[pcb + 1 * PITCH] = gray(pr.y, pg.y, pc.y);
    sP1[pcb + 2 * PITCH] = gray(pr.z, pg.z, pc.z);
    sP1[pcb + 3 * PITCH] = gray(pr.w, pg.w, pc.w);
    sT1[pcb + 0 * PITCH] = gray(tr.x, tg.x, tc.x);
    sT1[pcb + 1 * PITCH] = gray(tr.y, tg.y, tc.y);
    sT1[pcb + 2 * PITCH] = gray(tr.z, tg.z, tc.z);
    sT1[pcb + 3 * PITCH] = gray(tr.w, tg.w, tc.w);
    if (tid < XSETS)
        stage_set(pb, tb, ty0B, tx0, tid + NT, sP1, sT1, fastx);
    __syncthreads();

    cnt += compute_tile(sP1, sT1);

    // Reduce: 64-lane shuffle, cross-wave LDS, one atomic per block.
    #pragma unroll
    for (int o = 32; o > 0; o >>= 1) cnt += __shfl_down(cnt, o, 64);
    __shared__ int wsum[8];
    const int wv = threadIdx.x >> 6;
    if ((threadIdx.x & 63) == 0) wsum[wv] = cnt;
    __syncthreads();
    if (threadIdx.x == 0) {
        int tot = 0;
        #pragma unroll
        for (int w = 0; w < 8; ++w) tot += wsum[w];
        // N = 8 * 48 * 512 * 512 = 100663296
        atomicAdd(out, (float)tot * (1.0f / 100663296.0f));
    }
}

extern "C" void kernel_launch(void* const* d_in, const int* in_sizes, int n_in,
                              void* d_out, int out_size, void* d_ws, size_t ws_size,
                              hipStream_t stream) {
    const float* pred   = (const float*)d_in[0];
    const float* target = (const float*)d_in[1];
    float* out = (float*)d_out;

    hipMemsetAsync(out, 0, sizeof(float), stream);   // d_out poisoned 0xAA

    dim3 grid(WW / TW, HH / (2 * TH), BATCH);        // (8, 8, 8) = 512 blocks
    census_fused<<<grid, NT, 0, stream>>>(pred, target, out);
}

// Round 5
// 105.684 us; speedup vs baseline: 1.2023x; 1.1691x over previous
//
#include <hip/hip_runtime.h>

// CensusLoss = mean |census(pred)-census(target)| = mismatch_count / (8*48*512*512).
// R16 kernel — R15 pipeline with the VGPR cap fixed (launch_bounds 4 -> 2).
// Two vertically-adjacent 64x32 tiles per block, double-buffered LDS.
// ONE set per thread (6 named float4, 24 VGPR, unconditional) is prefetched
// for tile B before compute(A); the 172-set tail is staged after compute(A).
//
// Session ledger (why this exact shape):
//  - Divergent wave-split pipelines (R4-R6): scratch spills, 1.6-2x. Banned.
//  - In-tile sandwich (R8): no gain. Cross-tile pipeline moves the vmcnt
//    drain AFTER a full compute phase.
//  - Symmetry-halving (R9-R11): exact, never faster. Banned.
//  - Ballot/popcount SALU accumulation (R12): 26 -> 55us. Banned.
//  - RPT=8 (R13): neutral -> compute not LDS-issue-bound.
//  - R14: 2x Set6 conditional-live prefetch -> spill (WRITE 73.7MB). Banned.
//  - R15: 1-set named prefetch, STILL spilled (WRITE 47MB) because
//    __launch_bounds__(512,4) capped VGPR at 64 (4 blk-equiv x 8 waves =
//    32 waves/CU -> 2048/32 = 64). Needed ~75. The pipeline never had a
//    fair trial. R16 = R15 + launch_bounds(512,2) -> cap 128.
// Pass/fail counters: VGPR_Count ~85-110, WRITE_SIZE ~2MB, FETCH ~52MB.

#define BATCH 8
#define HH 512
#define WW 512
#define PLANE (HH * WW)
#define TW 64
#define TH 32
#define SCOLS 72          // staged cols: gx = tx0-4+lx
#define HROWS 38          // halo rows:  gy = ty0-3+hy
#define KPR 18            // float4 chunks per halo row (72/4)
#define PITCH 44
#define NT 512
#define LDSZ (SCOLS * PITCH)   // 3168 dwords per array
#define NSETS (HROWS * KPR)    // 684 float4-sets per tile
#define XSETS (NSETS - NT)     // 172 tail sets

__device__ __forceinline__ int refl(int v, int n) {
    return v < 0 ? -v : (v >= n ? 2 * n - 2 - v : v);
}
__device__ __forceinline__ int cbase(int lx) {      // swizzled column base
    return lx * PITCH + (((lx >> 2) & 7) << 2);     // stays 0 mod 4 -> 16B cols
}
__device__ __forceinline__ float gray(float r, float g, float b) {
    return 0.299f * r + 0.587f * g + 0.114f * b;
}

// Stage one 4-column set (load + gray + LDS write). Block-uniform `fast`.
__device__ __forceinline__ void stage_set(const float* __restrict__ pb,
                                          const float* __restrict__ tb,
                                          int ty0, int tx0, int sidx,
                                          float* __restrict__ sP,
                                          float* __restrict__ sT, bool fast) {
    const int hy = sidx / KPR;
    const int k  = sidx - hy * KPR;
    const int gy = refl(ty0 + hy - 3, HH);
    const int cb = cbase(4 * k) + hy;   // cbase(4k+i) = cbase(4k) + i*PITCH
    if (fast) {
        const int off = gy * WW + tx0 - 4 + 4 * k;            // 16B-aligned
        const float4 pr = *(const float4*)(pb + off);
        const float4 pg = *(const float4*)(pb + off + PLANE);
        const float4 pc = *(const float4*)(pb + off + 2 * PLANE);
        const float4 tr = *(const float4*)(tb + off);
        const float4 tg = *(const float4*)(tb + off + PLANE);
        const float4 tc = *(const float4*)(tb + off + 2 * PLANE);
        sP[cb + 0 * PITCH] = gray(pr.x, pg.x, pc.x);
        sP[cb + 1 * PITCH] = gray(pr.y, pg.y, pc.y);
        sP[cb + 2 * PITCH] = gray(pr.z, pg.z, pc.z);
        sP[cb + 3 * PITCH] = gray(pr.w, pg.w, pc.w);
        sT[cb + 0 * PITCH] = gray(tr.x, tg.x, tc.x);
        sT[cb + 1 * PITCH] = gray(tr.y, tg.y, tc.y);
        sT[cb + 2 * PITCH] = gray(tr.z, tg.z, tc.z);
        sT[cb + 3 * PITCH] = gray(tr.w, tg.w, tc.w);
    } else {
        #pragma unroll
        for (int i = 0; i < 4; ++i) {
            const int gx  = refl(tx0 - 4 + 4 * k + i, WW);
            const int off = gy * WW + gx;
            sP[cb + i * PITCH] = gray(pb[off], pb[off + PLANE], pb[off + 2 * PLANE]);
            sT[cb + i * PITCH] = gray(tb[off], tb[off + PLANE], tb[off + 2 * PLANE]);
        }
    }
}

// Load 10 consecutive column floats (16B-aligned) into registers.
__device__ __forceinline__ void load_col10(const float* col, float (&w)[10]) {
    const float4 a = *(const float4*)(col);
    const float4 b = *(const float4*)(col + 4);
    const float2 d = *(const float2*)(col + 8);
    w[0] = a.x; w[1] = a.y; w[2] = a.z; w[3] = a.w;
    w[4] = b.x; w[5] = b.y; w[6] = b.z; w[7] = b.w;
    w[8] = d.x; w[9] = d.y;
}

// R7-verbatim compute phase: per-lane predicated mismatch count for one tile.
__device__ __forceinline__ int compute_tile(const float* __restrict__ sP,
                                            const float* __restrict__ sT) {
    const int wv  = threadIdx.x >> 6;   // wave == 4-row band
    const int c   = threadIdx.x & 63;   // pixel column in tile
    const int pr0 = wv * 4;             // first pixel row (0,4,..,28)

    float wP[10], wT[10], cP[4], cT[4];
    int cnt = 0;
    load_col10(&sP[cbase(c + 4) + pr0], wP);        // dx = 0 column (centers)
    load_col10(&sT[cbase(c + 4) + pr0], wT);
    #pragma unroll
    for (int p = 0; p < 4; ++p) { cP[p] = wP[3 + p]; cT[p] = wT[3 + p]; }
    #pragma unroll
    for (int p = 0; p < 4; ++p) {
        #pragma unroll
        for (int dy = -3; dy <= 3; ++dy) {
            if (dy == 0) continue;                  // skip center
            cnt += ((cP[p] > wP[3 + p + dy]) != (cT[p] > wT[3 + p + dy])) ? 1 : 0;
        }
    }
    #pragma unroll
    for (int t = 0; t < 6; ++t) {
        const int lx = c + 1 + (t < 3 ? t : t + 1); // dx = -3..3, dx != 0
        load_col10(&sP[cbase(lx) + pr0], wP);
        load_col10(&sT[cbase(lx) + pr0], wT);
        #pragma unroll
        for (int p = 0; p < 4; ++p) {
            #pragma unroll
            for (int dy = -3; dy <= 3; ++dy)
                cnt += ((cP[p] > wP[3 + p + dy]) != (cT[p] > wT[3 + p + dy])) ? 1 : 0;
        }
    }
    return cnt;
}

__global__ __launch_bounds__(NT, 2)
void census_fused(const float* __restrict__ pred,
                  const float* __restrict__ target,
                  float* __restrict__ out) {
    __shared__ __align__(16) float sP0[LDSZ];
    __shared__ __align__(16) float sT0[LDSZ];
    __shared__ __align__(16) float sP1[LDSZ];
    __shared__ __align__(16) float sT1[LDSZ];

    const int b    = blockIdx.z;
    const int tx0  = blockIdx.x * TW;
    const int ty0A = (blockIdx.y * 2 + 0) * TH;     // two vertically-adjacent tiles
    const int ty0B = (blockIdx.y * 2 + 1) * TH;
    const float* __restrict__ pb = pred   + (size_t)b * 3 * PLANE;
    const float* __restrict__ tb = target + (size_t)b * 3 * PLANE;
    const int  tid  = threadIdx.x;
    const bool fastx = (blockIdx.x >= 1 && blockIdx.x <= 6);

    // ---- stage tile A fully (prologue, exposed) ----
    for (int idx = tid; idx < NSETS; idx += NT)
        stage_set(pb, tb, ty0A, tx0, idx, sP0, sT0, fastx);
    __syncthreads();

    // ---- prefetch ONE set of tile B per thread: 6 named float4, uniform ----
    float4 pr, pg, pc, tr, tg, tc;
    int pcb;
    {
        const int hy = tid / KPR;
        const int k  = tid - hy * KPR;
        const int gy = refl(ty0B + hy - 3, HH);
        pcb = cbase(4 * k) + hy;
        if (fastx) {
            const int off = gy * WW + tx0 - 4 + 4 * k;        // 16B-aligned
            pr = *(const float4*)(pb + off);
            pg = *(const float4*)(pb + off + PLANE);
            pc = *(const float4*)(pb + off + 2 * PLANE);
            tr = *(const float4*)(tb + off);
            tg = *(const float4*)(tb + off + PLANE);
            tc = *(const float4*)(tb + off + 2 * PLANE);
        } else {                                              // block-uniform
            const int o0 = gy * WW + refl(tx0 - 4 + 4 * k + 0, WW);
            const int o1 = gy * WW + refl(tx0 - 4 + 4 * k + 1, WW);
            const int o2 = gy * WW + refl(tx0 - 4 + 4 * k + 2, WW);
            const int o3 = gy * WW + refl(tx0 - 4 + 4 * k + 3, WW);
            pr = make_float4(pb[o0], pb[o1], pb[o2], pb[o3]);
            pg = make_float4(pb[o0 + PLANE], pb[o1 + PLANE], pb[o2 + PLANE], pb[o3 + PLANE]);
            pc = make_float4(pb[o0 + 2 * PLANE], pb[o1 + 2 * PLANE], pb[o2 + 2 * PLANE], pb[o3 + 2 * PLANE]);
            tr = make_float4(tb[o0], tb[o1], tb[o2], tb[o3]);
            tg = make_float4(tb[o0 + PLANE], tb[o1 + PLANE], tb[o2 + PLANE], tb[o3 + PLANE]);
            tc = make_float4(tb[o0 + 2 * PLANE], tb[o1 + 2 * PLANE], tb[o2 + 2 * PLANE], tb[o3 + 2 * PLANE]);
        }
    }
    __builtin_amdgcn_sched_barrier(0);   // pin the prefetch issue above compute(A)

    // ---- compute tile A while tile B loads are in flight ----
    int cnt = compute_tile(sP0, sT0);

    // ---- land prefetched set, stage 172-set tail, sync ----
    sP1[pcb + 0 * PITCH] = gray(pr.x, pg.x, pc.x);
    sP1[pcb + 1 * PITCH] = gray(pr.y, pg.y, pc.y);
    sP1[pcb + 2 * PITCH] = gray(pr.z, pg.z, pc.z);
    sP1[pcb + 3 * PITCH] = gray(pr.w, pg.w, pc.w);
    sT1[pcb + 0 * PITCH] = gray(tr.x, tg.x, tc.x);
    sT1[pcb + 1 * PITCH] = gray(tr.y, tg.y, tc.y);
    sT1[pcb + 2 * PITCH] = gray(tr.z, tg.z, tc.z);
    sT1[pcb + 3 * PITCH] = gray(tr.w, tg.w, tc.w);
    if (tid < XSETS)
        stage_set(pb, tb, ty0B, tx0, tid + NT, sP1, sT1, fastx);
    __syncthreads();

    cnt += compute_tile(sP1, sT1);

    // Reduce: 64-lane shuffle, cross-wave LDS, one atomic per block.
    #pragma unroll
    for (int o = 32; o > 0; o >>= 1) cnt += __shfl_down(cnt, o, 64);
    __shared__ int wsum[8];
    const int wv = threadIdx.x >> 6;
    if ((threadIdx.x & 63) == 0) wsum[wv] = cnt;
    __syncthreads();
    if (threadIdx.x == 0) {
        int tot = 0;
        #pragma unroll
        for (int w = 0; w < 8; ++w) tot += wsum[w];
        // N = 8 * 48 * 512 * 512 = 100663296
        atomicAdd(out, (float)tot * (1.0f / 100663296.0f));
    }
}

extern "C" void kernel_launch(void* const* d_in, const int* in_sizes, int n_in,
                              void* d_out, int out_size, void* d_ws, size_t ws_size,
                              hipStream_t stream) {
    const float* pred   = (const float*)d_in[0];
    const float* target = (const float*)d_in[1];
    float* out = (float*)d_out;

    hipMemsetAsync(out, 0, sizeof(float), stream);   // d_out poisoned 0xAA

    dim3 grid(WW / TW, HH / (2 * TH), BATCH);        // (8, 8, 8) = 512 blocks
    census_fused<<<grid, NT, 0, stream>>>(pred, target, out);
}

// Round 6
// 99.243 us; speedup vs baseline: 1.2804x; 1.0649x over previous
//
#include <hip/hip_runtime.h>

// CensusLoss = mean |census(pred)-census(target)| = mismatch_count / (8*48*512*512).
// R17 kernel == R7 (measured best: 98.8 / 99.6 / 100.9 across 3 runs).
// Fused: gray-on-the-fly into column-major LDS halo, b128 window reads,
// per-lane predicated mismatch count, one atomic per block.
//
// Session ledger (why this exact shape — 16 structural variants measured):
//  - 64x32 tile, 512 threads, RPT=4, stage -> ONE sync -> ONE uniform compute
//    site, 4 blocks/CU. This is the optimum.
//  - Divergent wave-split pipelines (R4-R6): scratch spills, 1.6-2x. Banned.
//  - In-tile sandwich overlap (R8): no gain. Banned.
//  - Symmetry-halving T=2*S+C (R9-R11): exact but never faster. Banned.
//  - Ballot/popcount SALU accumulation (R12): census 26 -> 55us. Scalar unit
//    is CU-shared (1 per 4 SIMDs); v_cmp->SGPR->SALU chains stall issue.
//    Banned.
//  - RPT=8 / 64x64 (R13): neutral (99.6) -> compute is NOT LDS-issue-bound.
//  - Cross-tile register-prefetch pipeline (R14-R16): R14/R15 spilled
//    (conditional-live Set6 state); R16 ran clean and STILL lost ~5us vs R7
//    (50KB dbuf LDS + halved grid -> 2-3 blk/CU; exposed-phase TLP loss >
//    hidden-latency gain). Cross-tile pipelining: banned.
//  - Structural accounting: ~73us fixed harness poison fills; census ~26us =
//    ~8us HBM fetch floor (50.3MB) + ~7us LDS-pipe + ~4us VALU + phase
//    serialization. All overlap and compute levers measured neutral/worse.
//    This is the structural floor.

#define BATCH 8
#define HH 512
#define WW 512
#define PLANE (HH * WW)
#define TW 64
#define TH 32
#define SCOLS 72          // staged cols: gx = tx0-4+lx (f4-aligned)
#define HROWS 38          // halo rows:  gy = ty0-3+hy
#define KPR 18            // float4 chunks per halo row (72/4)
#define PITCH 44
#define NT 512
#define LDSZ (SCOLS * PITCH)   // 3168 dwords; max index 71*44+4+37 = 3165

__device__ __forceinline__ int refl(int v, int n) {
    return v < 0 ? -v : (v >= n ? 2 * n - 2 - v : v);
}
__device__ __forceinline__ int cbase(int lx) {      // swizzled column base
    return lx * PITCH + (((lx >> 2) & 7) << 2);     // stays 0 mod 4 -> 16B cols
}

// Load 10 consecutive column floats (16B-aligned) into registers.
__device__ __forceinline__ void load_col10(const float* col, float (&w)[10]) {
    const float4 a = *(const float4*)(col);
    const float4 b = *(const float4*)(col + 4);
    const float2 d = *(const float2*)(col + 8);
    w[0] = a.x; w[1] = a.y; w[2] = a.z; w[3] = a.w;
    w[4] = b.x; w[5] = b.y; w[6] = b.z; w[7] = b.w;
    w[8] = d.x; w[9] = d.y;
}

__global__ __launch_bounds__(NT, 8)
void census_fused(const float* __restrict__ pred,
                  const float* __restrict__ target,
                  float* __restrict__ out) {
    __shared__ __align__(16) float sP[LDSZ];
    __shared__ __align__(16) float sT[LDSZ];

    const int b   = blockIdx.z;
    const int ty0 = blockIdx.y * TH;
    const int tx0 = blockIdx.x * TW;
    const float* __restrict__ pb = pred   + (size_t)b * 3 * PLANE;
    const float* __restrict__ tb = target + (size_t)b * 3 * PLANE;
    const bool fastx = (blockIdx.x >= 1 && blockIdx.x <= 6);  // gx always in range

    // ---- stage full 72x38 halo, then one barrier ----
    if (fastx) {
        for (int idx = threadIdx.x; idx < HROWS * KPR; idx += NT) {
            const int hy = idx / KPR;
            const int k  = idx - hy * KPR;
            const int gy  = refl(ty0 + hy - 3, HH);
            const int off = gy * WW + tx0 - 4 + 4 * k;        // 16B-aligned
            const float4 pr = *(const float4*)(pb + off);
            const float4 pg = *(const float4*)(pb + off + PLANE);
            const float4 pc = *(const float4*)(pb + off + 2 * PLANE);
            const float4 tr = *(const float4*)(tb + off);
            const float4 tg = *(const float4*)(tb + off + PLANE);
            const float4 tc = *(const float4*)(tb + off + 2 * PLANE);
            const int lx = 4 * k;
            sP[cbase(lx + 0) + hy] = 0.299f * pr.x + 0.587f * pg.x + 0.114f * pc.x;
            sP[cbase(lx + 1) + hy] = 0.299f * pr.y + 0.587f * pg.y + 0.114f * pc.y;
            sP[cbase(lx + 2) + hy] = 0.299f * pr.z + 0.587f * pg.z + 0.114f * pc.z;
            sP[cbase(lx + 3) + hy] = 0.299f * pr.w + 0.587f * pg.w + 0.114f * pc.w;
            sT[cbase(lx + 0) + hy] = 0.299f * tr.x + 0.587f * tg.x + 0.114f * tc.x;
            sT[cbase(lx + 1) + hy] = 0.299f * tr.y + 0.587f * tg.y + 0.114f * tc.y;
            sT[cbase(lx + 2) + hy] = 0.299f * tr.z + 0.587f * tg.z + 0.114f * tc.z;
            sT[cbase(lx + 3) + hy] = 0.299f * tr.w + 0.587f * tg.w + 0.114f * tc.w;
        }
    } else {
        for (int idx = threadIdx.x; idx < HROWS * SCOLS; idx += NT) {
            const int hy = idx / SCOLS;
            const int lx = idx - hy * SCOLS;
            const int gy  = refl(ty0 + hy - 3, HH);
            const int gx  = refl(tx0 + lx - 4, WW);
            const int off = gy * WW + gx;
            sP[cbase(lx) + hy] = 0.299f * pb[off] + 0.587f * pb[off + PLANE] + 0.114f * pb[off + 2 * PLANE];
            sT[cbase(lx) + hy] = 0.299f * tb[off] + 0.587f * tb[off + PLANE] + 0.114f * tb[off + 2 * PLANE];
        }
    }
    __syncthreads();

    const int wv  = threadIdx.x >> 6;   // wave == 4-row band
    const int c   = threadIdx.x & 63;   // pixel column in tile
    const int pr0 = wv * 4;             // first pixel row (0,4,..,28); pr0 % 4 == 0

    // Pixel (tx0+c, ty0+pr0+p), p=0..3: center at col c+4, halo row pr0+3+p;
    // window cols lx = c+1..c+7, halo rows pr0..pr0+9. Single call site.
    float wP[10], wT[10], cP[4], cT[4];
    int cnt = 0;
    load_col10(&sP[cbase(c + 4) + pr0], wP);        // dx = 0 column (holds centers)
    load_col10(&sT[cbase(c + 4) + pr0], wT);
    #pragma unroll
    for (int p = 0; p < 4; ++p) { cP[p] = wP[3 + p]; cT[p] = wT[3 + p]; }
    #pragma unroll
    for (int p = 0; p < 4; ++p) {
        #pragma unroll
        for (int dy = -3; dy <= 3; ++dy) {
            if (dy == 0) continue;                  // skip center
            cnt += ((cP[p] > wP[3 + p + dy]) != (cT[p] > wT[3 + p + dy])) ? 1 : 0;
        }
    }
    #pragma unroll
    for (int t = 0; t < 6; ++t) {
        const int lx = c + 1 + (t < 3 ? t : t + 1); // dx = -3..3, dx != 0
        load_col10(&sP[cbase(lx) + pr0], wP);
        load_col10(&sT[cbase(lx) + pr0], wT);
        #pragma unroll
        for (int p = 0; p < 4; ++p) {
            #pragma unroll
            for (int dy = -3; dy <= 3; ++dy)
                cnt += ((cP[p] > wP[3 + p + dy]) != (cT[p] > wT[3 + p + dy])) ? 1 : 0;
        }
    }

    // Reduce: 64-lane shuffle, cross-wave LDS, one atomic per block.
    #pragma unroll
    for (int o = 32; o > 0; o >>= 1) cnt += __shfl_down(cnt, o, 64);
    __shared__ int wsum[8];
    if ((threadIdx.x & 63) == 0) wsum[wv] = cnt;
    __syncthreads();
    if (threadIdx.x == 0) {
        int tot = 0;
        #pragma unroll
        for (int w = 0; w < 8; ++w) tot += wsum[w];
        // N = 8 * 48 * 512 * 512 = 100663296
        atomicAdd(out, (float)tot * (1.0f / 100663296.0f));
    }
}

extern "C" void kernel_launch(void* const* d_in, const int* in_sizes, int n_in,
                              void* d_out, int out_size, void* d_ws, size_t ws_size,
                              hipStream_t stream) {
    const float* pred   = (const float*)d_in[0];
    const float* target = (const float*)d_in[1];
    float* out = (float*)d_out;

    hipMemsetAsync(out, 0, sizeof(float), stream);   // d_out poisoned 0xAA

    dim3 grid(WW / TW, HH / TH, BATCH);              // (8, 16, 8) = 1024 blocks
    census_fused<<<grid, NT, 0, stream>>>(pred, target, out);
}